// Round 6
// baseline (311.199 us; speedup 1.0000x reference)
//
#include <hip/hip_runtime.h>
#include <hip/hip_bf16.h>

#define Qn 2048
#define Kn 2048
#define Cin 128
#define Hn 8
#define CHn 32
#define HDn 256
#define NSPLIT 8
#define KP 68   // dbl row stride (halves): g-stride 4*KP = 136 words = 8 banks mod 32 -> conflict-free reads

typedef __attribute__((ext_vector_type(8))) short short8;
typedef __attribute__((ext_vector_type(4))) float f32x4;

static __device__ __forceinline__ unsigned short f2bf(float f) {
    unsigned int u = __float_as_uint(f);
    u += 0x7fffu + ((u >> 16) & 1u);
    return (unsigned short)(u >> 16);
}

// ---------------------------------------------------------------------------
// K1: projections. q=(qx@Wq)/sqrt(CH)->bf16 [Q][HD]; k=kvx@Wk->bf16 [K][HD];
//     v=kvx@Wv->bf16 TRANSPOSED [HD][K]; g=sigmoid(qx@Wg+bg)->f32 [Q][HD].
// ---------------------------------------------------------------------------
__global__ __launch_bounds__(256) void proj_kernel(
    const float* __restrict__ qx, const float* __restrict__ kvx,
    const float* __restrict__ Wq, const float* __restrict__ Wk,
    const float* __restrict__ Wv, const float* __restrict__ Wg,
    const float* __restrict__ bg,
    unsigned short* __restrict__ qb, unsigned short* __restrict__ kb,
    unsigned short* __restrict__ vtb, float* __restrict__ gb)
{
    const int mat = blockIdx.y;
    const int r0 = blockIdx.x * 8;
    const int j = threadIdx.x;
    const float* A = (mat == 0 || mat == 3) ? qx : kvx;
    const float* W = (mat == 0) ? Wq : (mat == 1) ? Wk : (mat == 2) ? Wv : Wg;
    const float* Ar = A + r0 * Cin;
    float acc[8] = {0.f, 0.f, 0.f, 0.f, 0.f, 0.f, 0.f, 0.f};
    for (int c = 0; c < Cin; ++c) {
        const float w = W[c * HDn + j];
        #pragma unroll
        for (int i = 0; i < 8; ++i)
            acc[i] = fmaf(Ar[i * Cin + c], w, acc[i]);
    }
    if (mat == 0) {
        const float s = 0.17677669529663687f; // 1/sqrt(32)
        #pragma unroll
        for (int i = 0; i < 8; ++i)
            qb[(r0 + i) * HDn + j] = f2bf(acc[i] * s);
    } else if (mat == 1) {
        #pragma unroll
        for (int i = 0; i < 8; ++i)
            kb[(r0 + i) * HDn + j] = f2bf(acc[i]);
    } else if (mat == 2) {
        unsigned short tmp[8];
        #pragma unroll
        for (int i = 0; i < 8; ++i) tmp[i] = f2bf(acc[i]);
        *(short8*)(vtb + (size_t)j * Kn + r0) = *(short8*)tmp;
    } else {
        const float b = bg[j];
        #pragma unroll
        for (int i = 0; i < 8; ++i)
            gb[(r0 + i) * HDn + j] = 1.f / (1.f + __expf(-(acc[i] + b)));
    }
}

// ---------------------------------------------------------------------------
// K2: fused attention, single-barrier double-buffered dist/bias staging.
// Grid 1024 = 128 q-tiles x 8 K-splits, 512 thr = 8 waves (wave == head).
// Staging map (R3): sk=(t>>1)&63, shg=t&1 -> lane PAIRS cover full 32-B dist
// chunks (guaranteed intra-instruction coalescing; FETCH ~79 MB proven).
// VMEM issue order per tile: kf -> vf -> dist prefetch. In-order vmcnt
// retirement => QK waits only kf, PV waits only vf, the dist prefetch for
// tile kt+1 stays in flight across the whole tile. One barrier per tile.
// No-max softmax (|logit| < 8 by construction).
// ---------------------------------------------------------------------------
__global__ __launch_bounds__(512, 6) void attn_kernel(
    const unsigned short* __restrict__ qb, const unsigned short* __restrict__ kb,
    const unsigned short* __restrict__ vtb,
    const float* __restrict__ bias, const float* __restrict__ dist,
    float* __restrict__ opart, float* __restrict__ lpart)
{
    __shared__ unsigned short ps[Hn][16][72];  // 18432 B, wave-local regions
    __shared__ _Float16 dbl[2][Hn * 16 * KP];  // 2 x 17408 B

    const int bx = blockIdx.x;
    const int qt = bx >> 3;
    const int sp = bx & 7;
    const int q0 = qt * 16;
    const int k00 = sp * 256;
    const int t = threadIdx.x;
    const int h = t >> 6;
    const int l = t & 63;
    const int g = l >> 4;
    const int n = l & 15;

    // staging coordinates (R3 map)
    const int sk = (t >> 1) & 63;
    const int shg = t & 1;
    const int sqb = t >> 7; // 0..3

    const short8 qf = *(const short8*)(qb + (q0 + n) * HDn + h * CHn + g * 8);

    f32x4 o0 = {0.f, 0.f, 0.f, 0.f};
    f32x4 o1 = {0.f, 0.f, 0.f, 0.f};
    float lacc[4] = {0.f, 0.f, 0.f, 0.f};
    unsigned short* psh = &ps[h][0][0];
    const f32x4 z = {0.f, 0.f, 0.f, 0.f};

    // prefetch + stage tile 0
    f32x4 dv[4];
    float bv[4];
    #pragma unroll
    for (int i = 0; i < 4; ++i) {
        const int qi = q0 + sqb + 4 * i;
        dv[i] = *(const f32x4*)(dist + ((size_t)qi * Kn + k00 + sk) * Hn + 4 * shg);
        bv[i] = bias[(size_t)qi * Kn + k00 + sk];
    }
    #pragma unroll
    for (int i = 0; i < 4; ++i) {
        #pragma unroll
        for (int j = 0; j < 4; ++j)
            dbl[0][((shg * 4 + j) * 16 + sqb + 4 * i) * KP + sk] = (_Float16)(dv[i][j] + bv[i]);
    }
    int buf = 0;

    for (int kt = 0; kt < 4; ++kt) {
        const int k0 = k00 + kt * 64;
        __syncthreads(); // dbl[buf] published; dbl[buf^1] free
        // kf loads first, then vf, then dist prefetch: waits on kf (QK) and
        // vf (PV) never drain the dist prefetch (in-order vmcnt retirement).
        short8 kfr[4];
        #pragma unroll
        for (int kkg = 0; kkg < 4; ++kkg)
            kfr[kkg] = *(const short8*)(kb + (k0 + kkg * 16 + n) * HDn + h * CHn + g * 8);
        short8 vfr[4];
        #pragma unroll
        for (int chunk = 0; chunk < 2; ++chunk) {
            vfr[2 * chunk]     = *(const short8*)(vtb + (h * CHn + n) * Kn + k0 + chunk * 32 + g * 8);
            vfr[2 * chunk + 1] = *(const short8*)(vtb + (h * CHn + 16 + n) * Kn + k0 + chunk * 32 + g * 8);
        }
        if (kt < 3) { // prefetch next tile into registers
            #pragma unroll
            for (int i = 0; i < 4; ++i) {
                const int qi = q0 + sqb + 4 * i;
                dv[i] = *(const f32x4*)(dist + ((size_t)qi * Kn + k0 + 64 + sk) * Hn + 4 * shg);
                bv[i] = bias[(size_t)qi * Kn + k0 + 64 + sk];
            }
        }
        // scores
        f32x4 sf[4];
        #pragma unroll
        for (int kkg = 0; kkg < 4; ++kkg)
            sf[kkg] = __builtin_amdgcn_mfma_f32_16x16x32_bf16(qf, kfr[kkg], z, 0, 0, 0);
        // p = exp(s + staged bias+dist); per-lane row sums
        const _Float16* dbh = dbl[buf] + h * 16 * KP;
        #pragma unroll
        for (int kkg = 0; kkg < 4; ++kkg) {
            #pragma unroll
            for (int r = 0; r < 4; ++r) {
                const float db = (float)dbh[(g * 4 + r) * KP + kkg * 16 + n];
                const float p = __expf(sf[kkg][r] + db);
                sf[kkg][r] = p;
                lacc[r] += p;
            }
        }
        // P: D-layout -> LDS bf16 (wave-local round trip)
        #pragma unroll
        for (int kkg = 0; kkg < 4; ++kkg) {
            #pragma unroll
            for (int r = 0; r < 4; ++r)
                psh[(g * 4 + r) * 72 + kkg * 16 + n] = f2bf(sf[kkg][r]);
        }
        // PV (vf already resident)
        #pragma unroll
        for (int chunk = 0; chunk < 2; ++chunk) {
            const short8 pf = *(const short8*)(psh + n * 72 + chunk * 32 + g * 8);
            o0 = __builtin_amdgcn_mfma_f32_16x16x32_bf16(pf, vfr[2 * chunk], o0, 0, 0, 0);
            o1 = __builtin_amdgcn_mfma_f32_16x16x32_bf16(pf, vfr[2 * chunk + 1], o1, 0, 0, 0);
        }
        // stage next tile into the other buffer (prefetch regs -> LDS)
        if (kt < 3) {
            #pragma unroll
            for (int i = 0; i < 4; ++i) {
                #pragma unroll
                for (int j = 0; j < 4; ++j)
                    dbl[buf ^ 1][((shg * 4 + j) * 16 + sqb + 4 * i) * KP + sk] = (_Float16)(dv[i][j] + bv[i]);
            }
        }
        buf ^= 1;
    }
    // write partial O and row-sums
    float* op = opart + (size_t)sp * (Qn * HDn);
    #pragma unroll
    for (int r = 0; r < 4; ++r) {
        const int qg = q0 + g * 4 + r;
        op[qg * HDn + h * CHn + n] = o0[r];
        op[qg * HDn + h * CHn + 16 + n] = o1[r];
        float v = lacc[r];
        v += __shfl_xor(v, 1);
        v += __shfl_xor(v, 2);
        v += __shfl_xor(v, 4);
        v += __shfl_xor(v, 8);
        lacc[r] = v;
    }
    if (n == 0) {
        float* lp = lpart + (size_t)sp * (Qn * Hn);
        #pragma unroll
        for (int r = 0; r < 4; ++r)
            lp[(q0 + g * 4 + r) * Hn + h] = lacc[r];
    }
}

// ---------------------------------------------------------------------------
// K3: merge splits + gating + output projection. One block per q-row.
// ---------------------------------------------------------------------------
__global__ __launch_bounds__(256) void mergeout_kernel(
    const float* __restrict__ opart, const float* __restrict__ lpart,
    const float* __restrict__ gb, const float* __restrict__ Wo,
    const float* __restrict__ bo, float* __restrict__ out)
{
    __shared__ float olds[HDn];
    __shared__ float red[4][128];
    const int q = blockIdx.x;
    const int t = threadIdx.x;
    const int h = t >> 5;
    float s = 0.f;
    #pragma unroll
    for (int sp = 0; sp < NSPLIT; ++sp)
        s += opart[(size_t)sp * (Qn * HDn) + q * HDn + t];
    float lt = 0.f;
    #pragma unroll
    for (int sp = 0; sp < NSPLIT; ++sp)
        lt += lpart[(size_t)sp * (Qn * Hn) + q * Hn + h];
    olds[t] = (s / lt) * gb[q * HDn + t];
    __syncthreads();
    const int p = t & 63;
    const int seg = t >> 6;
    float a0 = 0.f, a1 = 0.f;
    for (int c = seg * 64; c < seg * 64 + 64; ++c) {
        const float ov = olds[c];
        const float2 w = *(const float2*)(Wo + c * Cin + 2 * p);
        a0 = fmaf(ov, w.x, a0);
        a1 = fmaf(ov, w.y, a1);
    }
    red[seg][2 * p] = a0;
    red[seg][2 * p + 1] = a1;
    __syncthreads();
    if (t < 128)
        out[q * Cin + t] = red[0][t] + red[1][t] + red[2][t] + red[3][t] + bo[t];
}

extern "C" void kernel_launch(void* const* d_in, const int* in_sizes, int n_in,
                              void* d_out, int out_size, void* d_ws, size_t ws_size,
                              hipStream_t stream)
{
    const float* qx   = (const float*)d_in[0];
    const float* kvx  = (const float*)d_in[1];
    const float* bias = (const float*)d_in[2];
    const float* dist = (const float*)d_in[3];
    const float* Wq   = (const float*)d_in[4];
    const float* Wk   = (const float*)d_in[5];
    const float* Wv   = (const float*)d_in[6];
    const float* Wg   = (const float*)d_in[7];
    const float* bg   = (const float*)d_in[8];
    const float* Wo   = (const float*)d_in[9];
    const float* bo   = (const float*)d_in[10];
    float* out = (float*)d_out;

    char* w = (char*)d_ws;
    unsigned short* qb  = (unsigned short*)(w);                  // 1 MB
    unsigned short* kb  = (unsigned short*)(w + (1ull << 20));   // 1 MB
    unsigned short* vtb = (unsigned short*)(w + (2ull << 20));   // 1 MB
    float* gb    = (float*)(w + (3ull << 20));                   // 2 MB
    float* opart = (float*)(w + (5ull << 20));                   // 16 MB (8 splits)
    float* lpart = (float*)(w + (21ull << 20));                  // 512 KB

    proj_kernel<<<dim3(Qn / 8, 4), 256, 0, stream>>>(qx, kvx, Wq, Wk, Wv, Wg, bg, qb, kb, vtb, gb);
    attn_kernel<<<dim3(128 * NSPLIT), 512, 0, stream>>>(qb, kb, vtb, bias, dist, opart, lpart);
    mergeout_kernel<<<dim3(Qn), 256, 0, stream>>>(opart, lpart, gb, Wo, bo, out);
}

// Round 7
// 295.831 us; speedup vs baseline: 1.0519x; 1.0519x over previous
//
#include <hip/hip_runtime.h>
#include <hip/hip_bf16.h>

#define Qn 2048
#define Kn 2048
#define Cin 128
#define Hn 8
#define CHn 32
#define HDn 256
#define NSPLIT 16
#define KP 68   // dbl row stride (halves): head-block stride 16*KP, g-stride 4*KP = 136 words = 8 banks mod 32 -> conflict-free reads

typedef __attribute__((ext_vector_type(8))) short short8;
typedef __attribute__((ext_vector_type(4))) float f32x4;

static __device__ __forceinline__ unsigned short f2bf(float f) {
    unsigned int u = __float_as_uint(f);
    u += 0x7fffu + ((u >> 16) & 1u);
    return (unsigned short)(u >> 16);
}

// ---------------------------------------------------------------------------
// K1: projections. q=(qx@Wq)/sqrt(CH)->bf16 [Q][HD]; k=kvx@Wk->bf16 [K][HD];
//     v=kvx@Wv->bf16 TRANSPOSED [HD][K]; g=sigmoid(qx@Wg+bg)->f32 [Q][HD].
// ---------------------------------------------------------------------------
__global__ __launch_bounds__(256) void proj_kernel(
    const float* __restrict__ qx, const float* __restrict__ kvx,
    const float* __restrict__ Wq, const float* __restrict__ Wk,
    const float* __restrict__ Wv, const float* __restrict__ Wg,
    const float* __restrict__ bg,
    unsigned short* __restrict__ qb, unsigned short* __restrict__ kb,
    unsigned short* __restrict__ vtb, float* __restrict__ gb)
{
    const int mat = blockIdx.y;
    const int r0 = blockIdx.x * 8;
    const int j = threadIdx.x;
    const float* A = (mat == 0 || mat == 3) ? qx : kvx;
    const float* W = (mat == 0) ? Wq : (mat == 1) ? Wk : (mat == 2) ? Wv : Wg;
    const float* Ar = A + r0 * Cin;
    float acc[8] = {0.f, 0.f, 0.f, 0.f, 0.f, 0.f, 0.f, 0.f};
    for (int c = 0; c < Cin; ++c) {
        const float w = W[c * HDn + j];
        #pragma unroll
        for (int i = 0; i < 8; ++i)
            acc[i] = fmaf(Ar[i * Cin + c], w, acc[i]);
    }
    if (mat == 0) {
        const float s = 0.17677669529663687f; // 1/sqrt(32)
        #pragma unroll
        for (int i = 0; i < 8; ++i)
            qb[(r0 + i) * HDn + j] = f2bf(acc[i] * s);
    } else if (mat == 1) {
        #pragma unroll
        for (int i = 0; i < 8; ++i)
            kb[(r0 + i) * HDn + j] = f2bf(acc[i]);
    } else if (mat == 2) {
        unsigned short tmp[8];
        #pragma unroll
        for (int i = 0; i < 8; ++i) tmp[i] = f2bf(acc[i]);
        *(short8*)(vtb + (size_t)j * Kn + r0) = *(short8*)tmp;
    } else {
        const float b = bg[j];
        #pragma unroll
        for (int i = 0; i < 8; ++i)
            gb[(r0 + i) * HDn + j] = 1.f / (1.f + __expf(-(acc[i] + b)));
    }
}

// ---------------------------------------------------------------------------
// K2: fused attention, 256 thr = 4 waves = 4 heads (one h-group of the 8).
// Grid 4096 = 128 q-tiles x 16 K-splits x 2 h-groups (hg = bx&1 so the two
// complementary h-group blocks are grid-adjacent -> L2 reuse of dist lines).
// Per 64-k tile: R3-proven 2-barrier staging of fp16(bias+dist) into LDS,
// but now each lane loads exactly ONE f32x4 = its h-group's 4 heads of one
// (q,k) -> 16 B/lane coalescing sweet spot, zero waste in-block.
// Small LDS (17.9 KB) + small live set -> 6 blocks/CU resident, 24 waves/CU.
// No-max softmax (|logit| < 8 by construction).
// ---------------------------------------------------------------------------
__global__ __launch_bounds__(256, 6) void attn_kernel(
    const unsigned short* __restrict__ qb, const unsigned short* __restrict__ kb,
    const unsigned short* __restrict__ vtb,
    const float* __restrict__ bias, const float* __restrict__ dist,
    float* __restrict__ opart, float* __restrict__ lpart)
{
    __shared__ unsigned short ps[4][16][72]; // 9216 B, wave-local regions
    __shared__ _Float16 dbl[4 * 16 * KP];    // 8704 B

    const int bx = blockIdx.x;
    const int hg = bx & 1;
    const int sp = (bx >> 1) & (NSPLIT - 1);
    const int qt = bx >> 5;
    const int q0 = qt * 16;
    const int k00 = sp * (Kn / NSPLIT); // 128
    const int hbase = hg * 4;
    const int t = threadIdx.x;
    const int w = t >> 6;        // wave = local head
    const int h = hbase + w;     // global head
    const int l = t & 63;
    const int g = l >> 4;
    const int n = l & 15;

    // staging coordinates: lane covers (q = sq + 4i, k = sk), 4 heads via f32x4
    const int sk = t & 63;
    const int sq = t >> 6; // 0..3

    const short8 qf = *(const short8*)(qb + (q0 + n) * HDn + h * CHn + g * 8);

    f32x4 o0 = {0.f, 0.f, 0.f, 0.f};
    f32x4 o1 = {0.f, 0.f, 0.f, 0.f};
    float lacc[4] = {0.f, 0.f, 0.f, 0.f};
    unsigned short* psh = &ps[w][0][0];
    const f32x4 z = {0.f, 0.f, 0.f, 0.f};

    // prefetch tile 0
    f32x4 dv[4];
    float bv[4];
    #pragma unroll
    for (int i = 0; i < 4; ++i) {
        const int qi = q0 + sq + 4 * i;
        dv[i] = *(const f32x4*)(dist + ((size_t)qi * Kn + k00 + sk) * Hn + 4 * hg);
        bv[i] = bias[(size_t)qi * Kn + k00 + sk];
    }

    for (int kt = 0; kt < Kn / NSPLIT / 64; ++kt) { // 2 tiles
        const int k0 = k00 + kt * 64;
        __syncthreads(); // previous tile's dbl fully consumed
        #pragma unroll
        for (int i = 0; i < 4; ++i) {
            #pragma unroll
            for (int j = 0; j < 4; ++j)
                dbl[(j * 16 + sq + 4 * i) * KP + sk] = (_Float16)(dv[i][j] + bv[i]);
        }
        __syncthreads();
        if (kt < 1) { // prefetch next tile
            #pragma unroll
            for (int i = 0; i < 4; ++i) {
                const int qi = q0 + sq + 4 * i;
                dv[i] = *(const f32x4*)(dist + ((size_t)qi * Kn + k0 + 64 + sk) * Hn + 4 * hg);
                bv[i] = bias[(size_t)qi * Kn + k0 + 64 + sk];
            }
        }
        // scores
        f32x4 sf[4];
        #pragma unroll
        for (int kkg = 0; kkg < 4; ++kkg) {
            const short8 kf = *(const short8*)(kb + (k0 + kkg * 16 + n) * HDn + h * CHn + g * 8);
            sf[kkg] = __builtin_amdgcn_mfma_f32_16x16x32_bf16(qf, kf, z, 0, 0, 0);
        }
        // p = exp(s + staged bias+dist); per-lane row sums
        const _Float16* dbh = dbl + w * 16 * KP;
        #pragma unroll
        for (int kkg = 0; kkg < 4; ++kkg) {
            #pragma unroll
            for (int r = 0; r < 4; ++r) {
                const float db = (float)dbh[(g * 4 + r) * KP + kkg * 16 + n];
                const float p = __expf(sf[kkg][r] + db);
                sf[kkg][r] = p;
                lacc[r] += p;
            }
        }
        // P: D-layout -> LDS bf16 (wave-local round trip)
        #pragma unroll
        for (int kkg = 0; kkg < 4; ++kkg) {
            #pragma unroll
            for (int r = 0; r < 4; ++r)
                psh[(g * 4 + r) * 72 + kkg * 16 + n] = f2bf(sf[kkg][r]);
        }
        // PV
        #pragma unroll
        for (int chunk = 0; chunk < 2; ++chunk) {
            const short8 pf = *(const short8*)(psh + n * 72 + chunk * 32 + g * 8);
            const short8 vf0 = *(const short8*)(vtb + (h * CHn + n) * Kn + k0 + chunk * 32 + g * 8);
            o0 = __builtin_amdgcn_mfma_f32_16x16x32_bf16(pf, vf0, o0, 0, 0, 0);
            const short8 vf1 = *(const short8*)(vtb + (h * CHn + 16 + n) * Kn + k0 + chunk * 32 + g * 8);
            o1 = __builtin_amdgcn_mfma_f32_16x16x32_bf16(pf, vf1, o1, 0, 0, 0);
        }
    }
    // write partial O and row-sums
    float* op = opart + (size_t)sp * (Qn * HDn);
    #pragma unroll
    for (int r = 0; r < 4; ++r) {
        const int qg = q0 + g * 4 + r;
        op[qg * HDn + h * CHn + n] = o0[r];
        op[qg * HDn + h * CHn + 16 + n] = o1[r];
        float v = lacc[r];
        v += __shfl_xor(v, 1);
        v += __shfl_xor(v, 2);
        v += __shfl_xor(v, 4);
        v += __shfl_xor(v, 8);
        lacc[r] = v;
    }
    if (n == 0) {
        float* lp = lpart + (size_t)sp * (Qn * Hn);
        #pragma unroll
        for (int r = 0; r < 4; ++r)
            lp[(q0 + g * 4 + r) * Hn + h] = lacc[r];
    }
}

// ---------------------------------------------------------------------------
// K3: merge splits + gating + output projection. One block per q-row.
// ---------------------------------------------------------------------------
__global__ __launch_bounds__(256) void mergeout_kernel(
    const float* __restrict__ opart, const float* __restrict__ lpart,
    const float* __restrict__ gb, const float* __restrict__ Wo,
    const float* __restrict__ bo, float* __restrict__ out)
{
    __shared__ float olds[HDn];
    __shared__ float red[4][128];
    const int q = blockIdx.x;
    const int t = threadIdx.x;
    const int h = t >> 5;
    float s = 0.f;
    #pragma unroll
    for (int sp = 0; sp < NSPLIT; ++sp)
        s += opart[(size_t)sp * (Qn * HDn) + q * HDn + t];
    float lt = 0.f;
    #pragma unroll
    for (int sp = 0; sp < NSPLIT; ++sp)
        lt += lpart[(size_t)sp * (Qn * Hn) + q * Hn + h];
    olds[t] = (s / lt) * gb[q * HDn + t];
    __syncthreads();
    const int p = t & 63;
    const int seg = t >> 6;
    float a0 = 0.f, a1 = 0.f;
    for (int c = seg * 64; c < seg * 64 + 64; ++c) {
        const float ov = olds[c];
        const float2 w = *(const float2*)(Wo + c * Cin + 2 * p);
        a0 = fmaf(ov, w.x, a0);
        a1 = fmaf(ov, w.y, a1);
    }
    red[seg][2 * p] = a0;
    red[seg][2 * p + 1] = a1;
    __syncthreads();
    if (t < 128)
        out[q * Cin + t] = red[0][t] + red[1][t] + red[2][t] + red[3][t] + bo[t];
}

extern "C" void kernel_launch(void* const* d_in, const int* in_sizes, int n_in,
                              void* d_out, int out_size, void* d_ws, size_t ws_size,
                              hipStream_t stream)
{
    const float* qx   = (const float*)d_in[0];
    const float* kvx  = (const float*)d_in[1];
    const float* bias = (const float*)d_in[2];
    const float* dist = (const float*)d_in[3];
    const float* Wq   = (const float*)d_in[4];
    const float* Wk   = (const float*)d_in[5];
    const float* Wv   = (const float*)d_in[6];
    const float* Wg   = (const float*)d_in[7];
    const float* bg   = (const float*)d_in[8];
    const float* Wo   = (const float*)d_in[9];
    const float* bo   = (const float*)d_in[10];
    float* out = (float*)d_out;

    char* w = (char*)d_ws;
    unsigned short* qb  = (unsigned short*)(w);                  // 1 MB
    unsigned short* kb  = (unsigned short*)(w + (1ull << 20));   // 1 MB
    unsigned short* vtb = (unsigned short*)(w + (2ull << 20));   // 1 MB
    float* gb    = (float*)(w + (3ull << 20));                   // 2 MB
    float* opart = (float*)(w + (5ull << 20));                   // 32 MB (16 splits)
    float* lpart = (float*)(w + (37ull << 20));                  // 1 MB

    proj_kernel<<<dim3(Qn / 8, 4), 256, 0, stream>>>(qx, kvx, Wq, Wk, Wv, Wg, bg, qb, kb, vtb, gb);
    attn_kernel<<<dim3(128 * NSPLIT * 2), 256, 0, stream>>>(qb, kb, vtb, bias, dist, opart, lpart);
    mergeout_kernel<<<dim3(Qn), 256, 0, stream>>>(opart, lpart, gb, Wo, bo, out);
}

// Round 8
// 288.071 us; speedup vs baseline: 1.0803x; 1.0269x over previous
//
#include <hip/hip_runtime.h>
#include <hip/hip_bf16.h>

#define Qn 2048
#define Kn 2048
#define Cin 128
#define Hn 8
#define CHn 32
#define HDn 256
#define NSPLIT 16
#define KP 68   // dbl row stride (halves)

typedef __attribute__((ext_vector_type(8))) short short8;
typedef __attribute__((ext_vector_type(4))) float f32x4;

static __device__ __forceinline__ unsigned short f2bf(float f) {
    unsigned int u = __float_as_uint(f);
    u += 0x7fffu + ((u >> 16) & 1u);
    return (unsigned short)(u >> 16);
}

// ---------------------------------------------------------------------------
// K1: projections. q=(qx@Wq)/sqrt(CH)->bf16 [Q][HD]; k=kvx@Wk->bf16 [K][HD];
//     v=kvx@Wv->bf16 TRANSPOSED [HD][K]; g=sigmoid(qx@Wg+bg)->f32 [Q][HD].
// ---------------------------------------------------------------------------
__global__ __launch_bounds__(256) void proj_kernel(
    const float* __restrict__ qx, const float* __restrict__ kvx,
    const float* __restrict__ Wq, const float* __restrict__ Wk,
    const float* __restrict__ Wv, const float* __restrict__ Wg,
    const float* __restrict__ bg,
    unsigned short* __restrict__ qb, unsigned short* __restrict__ kb,
    unsigned short* __restrict__ vtb, float* __restrict__ gb)
{
    const int mat = blockIdx.y;
    const int r0 = blockIdx.x * 8;
    const int j = threadIdx.x;
    const float* A = (mat == 0 || mat == 3) ? qx : kvx;
    const float* W = (mat == 0) ? Wq : (mat == 1) ? Wk : (mat == 2) ? Wv : Wg;
    const float* Ar = A + r0 * Cin;
    float acc[8] = {0.f, 0.f, 0.f, 0.f, 0.f, 0.f, 0.f, 0.f};
    for (int c = 0; c < Cin; ++c) {
        const float w = W[c * HDn + j];
        #pragma unroll
        for (int i = 0; i < 8; ++i)
            acc[i] = fmaf(Ar[i * Cin + c], w, acc[i]);
    }
    if (mat == 0) {
        const float s = 0.17677669529663687f; // 1/sqrt(32)
        #pragma unroll
        for (int i = 0; i < 8; ++i)
            qb[(r0 + i) * HDn + j] = f2bf(acc[i] * s);
    } else if (mat == 1) {
        #pragma unroll
        for (int i = 0; i < 8; ++i)
            kb[(r0 + i) * HDn + j] = f2bf(acc[i]);
    } else if (mat == 2) {
        unsigned short tmp[8];
        #pragma unroll
        for (int i = 0; i < 8; ++i) tmp[i] = f2bf(acc[i]);
        *(short8*)(vtb + (size_t)j * Kn + r0) = *(short8*)tmp;
    } else {
        const float b = bg[j];
        #pragma unroll
        for (int i = 0; i < 8; ++i)
            gb[(r0 + i) * HDn + j] = 1.f / (1.f + __expf(-(acc[i] + b)));
    }
}

// ---------------------------------------------------------------------------
// K2: fused attention = R3's proven structure (512 thr = 8 waves = 8 heads,
// 2-barrier LDS staging of fp16(bias+dist), lane-pair full-32B dist chunks)
// with NSPLIT 16: grid 2048 = 8 blocks/CU available, 4 resident (143 KB LDS)
// = 32 waves/CU. 2 serial k-tiles per block. No-max softmax (|logit| < 8).
// ---------------------------------------------------------------------------
__global__ __launch_bounds__(512, 8) void attn_kernel(
    const unsigned short* __restrict__ qb, const unsigned short* __restrict__ kb,
    const unsigned short* __restrict__ vtb,
    const float* __restrict__ bias, const float* __restrict__ dist,
    float* __restrict__ opart, float* __restrict__ lpart)
{
    __shared__ unsigned short ps[Hn][16][72]; // 18432 B, wave-local regions
    __shared__ _Float16 dbl[Hn * 16 * KP];    // 17408 B

    const int bx = blockIdx.x;
    const int qt = bx >> 4;
    const int sp = bx & (NSPLIT - 1);
    const int q0 = qt * 16;
    const int k00 = sp * (Kn / NSPLIT); // 128
    const int t = threadIdx.x;
    const int h = t >> 6;
    const int l = t & 63;
    const int g = l >> 4;
    const int n = l & 15;

    // staging coordinates: thread pairs cover full 32-B dist chunks
    const int sk = (t >> 1) & 63;
    const int shg = t & 1;
    const int sqb = t >> 7; // 0..3

    const short8 qf = *(const short8*)(qb + (q0 + n) * HDn + h * CHn + g * 8);

    f32x4 o0 = {0.f, 0.f, 0.f, 0.f};
    f32x4 o1 = {0.f, 0.f, 0.f, 0.f};
    float lacc[4] = {0.f, 0.f, 0.f, 0.f};
    unsigned short* psh = &ps[h][0][0];
    const f32x4 z = {0.f, 0.f, 0.f, 0.f};

    // prefetch tile 0
    f32x4 dv[4];
    float bv[4];
    #pragma unroll
    for (int i = 0; i < 4; ++i) {
        const int qi = q0 + sqb + 4 * i;
        dv[i] = *(const f32x4*)(dist + ((size_t)qi * Kn + k00 + sk) * Hn + 4 * shg);
        bv[i] = bias[(size_t)qi * Kn + k00 + sk];
    }

    for (int kt = 0; kt < Kn / NSPLIT / 64; ++kt) { // 2 tiles
        const int k0 = k00 + kt * 64;
        __syncthreads(); // previous tile's dbl fully consumed
        #pragma unroll
        for (int i = 0; i < 4; ++i) {
            #pragma unroll
            for (int j = 0; j < 4; ++j)
                dbl[((shg * 4 + j) * 16 + sqb + 4 * i) * KP + sk] = (_Float16)(dv[i][j] + bv[i]);
        }
        __syncthreads();
        if (kt < Kn / NSPLIT / 64 - 1) { // prefetch next tile
            #pragma unroll
            for (int i = 0; i < 4; ++i) {
                const int qi = q0 + sqb + 4 * i;
                dv[i] = *(const f32x4*)(dist + ((size_t)qi * Kn + k0 + 64 + sk) * Hn + 4 * shg);
                bv[i] = bias[(size_t)qi * Kn + k0 + 64 + sk];
            }
        }
        // scores
        f32x4 sf[4];
        #pragma unroll
        for (int kkg = 0; kkg < 4; ++kkg) {
            const short8 kf = *(const short8*)(kb + (k0 + kkg * 16 + n) * HDn + h * CHn + g * 8);
            sf[kkg] = __builtin_amdgcn_mfma_f32_16x16x32_bf16(qf, kf, z, 0, 0, 0);
        }
        // p = exp(s + staged bias+dist); per-lane row sums
        const _Float16* dbh = dbl + h * 16 * KP;
        #pragma unroll
        for (int kkg = 0; kkg < 4; ++kkg) {
            #pragma unroll
            for (int r = 0; r < 4; ++r) {
                const float db = (float)dbh[(g * 4 + r) * KP + kkg * 16 + n];
                const float p = __expf(sf[kkg][r] + db);
                sf[kkg][r] = p;
                lacc[r] += p;
            }
        }
        // P: D-layout -> LDS bf16 (wave-local round trip)
        #pragma unroll
        for (int kkg = 0; kkg < 4; ++kkg) {
            #pragma unroll
            for (int r = 0; r < 4; ++r)
                psh[(g * 4 + r) * 72 + kkg * 16 + n] = f2bf(sf[kkg][r]);
        }
        // PV
        #pragma unroll
        for (int chunk = 0; chunk < 2; ++chunk) {
            const short8 pf = *(const short8*)(psh + n * 72 + chunk * 32 + g * 8);
            const short8 vf0 = *(const short8*)(vtb + (h * CHn + n) * Kn + k0 + chunk * 32 + g * 8);
            o0 = __builtin_amdgcn_mfma_f32_16x16x32_bf16(pf, vf0, o0, 0, 0, 0);
            const short8 vf1 = *(const short8*)(vtb + (h * CHn + 16 + n) * Kn + k0 + chunk * 32 + g * 8);
            o1 = __builtin_amdgcn_mfma_f32_16x16x32_bf16(pf, vf1, o1, 0, 0, 0);
        }
    }
    // write partial O and row-sums
    float* op = opart + (size_t)sp * (Qn * HDn);
    #pragma unroll
    for (int r = 0; r < 4; ++r) {
        const int qg = q0 + g * 4 + r;
        op[qg * HDn + h * CHn + n] = o0[r];
        op[qg * HDn + h * CHn + 16 + n] = o1[r];
        float v = lacc[r];
        v += __shfl_xor(v, 1);
        v += __shfl_xor(v, 2);
        v += __shfl_xor(v, 4);
        v += __shfl_xor(v, 8);
        lacc[r] = v;
    }
    if (n == 0) {
        float* lp = lpart + (size_t)sp * (Qn * Hn);
        #pragma unroll
        for (int r = 0; r < 4; ++r)
            lp[(q0 + g * 4 + r) * Hn + h] = lacc[r];
    }
}

// ---------------------------------------------------------------------------
// K3: merge splits + gating + output projection. One block per q-row.
// ---------------------------------------------------------------------------
__global__ __launch_bounds__(256) void mergeout_kernel(
    const float* __restrict__ opart, const float* __restrict__ lpart,
    const float* __restrict__ gb, const float* __restrict__ Wo,
    const float* __restrict__ bo, float* __restrict__ out)
{
    __shared__ float olds[HDn];
    __shared__ float red[4][128];
    const int q = blockIdx.x;
    const int t = threadIdx.x;
    const int h = t >> 5;
    float s = 0.f;
    #pragma unroll
    for (int sp = 0; sp < NSPLIT; ++sp)
        s += opart[(size_t)sp * (Qn * HDn) + q * HDn + t];
    float lt = 0.f;
    #pragma unroll
    for (int sp = 0; sp < NSPLIT; ++sp)
        lt += lpart[(size_t)sp * (Qn * Hn) + q * Hn + h];
    olds[t] = (s / lt) * gb[q * HDn + t];
    __syncthreads();
    const int p = t & 63;
    const int seg = t >> 6;
    float a0 = 0.f, a1 = 0.f;
    for (int c = seg * 64; c < seg * 64 + 64; ++c) {
        const float ov = olds[c];
        const float2 w = *(const float2*)(Wo + c * Cin + 2 * p);
        a0 = fmaf(ov, w.x, a0);
        a1 = fmaf(ov, w.y, a1);
    }
    red[seg][2 * p] = a0;
    red[seg][2 * p + 1] = a1;
    __syncthreads();
    if (t < 128)
        out[q * Cin + t] = red[0][t] + red[1][t] + red[2][t] + red[3][t] + bo[t];
}

extern "C" void kernel_launch(void* const* d_in, const int* in_sizes, int n_in,
                              void* d_out, int out_size, void* d_ws, size_t ws_size,
                              hipStream_t stream)
{
    const float* qx   = (const float*)d_in[0];
    const float* kvx  = (const float*)d_in[1];
    const float* bias = (const float*)d_in[2];
    const float* dist = (const float*)d_in[3];
    const float* Wq   = (const float*)d_in[4];
    const float* Wk   = (const float*)d_in[5];
    const float* Wv   = (const float*)d_in[6];
    const float* Wg   = (const float*)d_in[7];
    const float* bg   = (const float*)d_in[8];
    const float* Wo   = (const float*)d_in[9];
    const float* bo   = (const float*)d_in[10];
    float* out = (float*)d_out;

    char* w = (char*)d_ws;
    unsigned short* qb  = (unsigned short*)(w);                  // 1 MB
    unsigned short* kb  = (unsigned short*)(w + (1ull << 20));   // 1 MB
    unsigned short* vtb = (unsigned short*)(w + (2ull << 20));   // 1 MB
    float* gb    = (float*)(w + (3ull << 20));                   // 2 MB
    float* opart = (float*)(w + (5ull << 20));                   // 32 MB (16 splits)
    float* lpart = (float*)(w + (37ull << 20));                  // 1 MB

    proj_kernel<<<dim3(Qn / 8, 4), 256, 0, stream>>>(qx, kvx, Wq, Wk, Wv, Wg, bg, qb, kb, vtb, gb);
    attn_kernel<<<dim3(128 * NSPLIT), 512, 0, stream>>>(qb, kb, vtb, bias, dist, opart, lpart);
    mergeout_kernel<<<dim3(Qn), 256, 0, stream>>>(opart, lpart, gb, Wo, bo, out);
}